// Round 5
// baseline (29692.175 us; speedup 1.0000x reference)
//
#include <hip/hip_runtime.h>
#include <hip/hip_bf16.h>
#include <hip/hip_cooperative_groups.h>

namespace cg = cooperative_groups;

#define DI __device__ __forceinline__

typedef short bf16x8 __attribute__((ext_vector_type(8)));
typedef float f32x4 __attribute__((ext_vector_type(4)));

constexpr int B_ = 2048, T_ = 120, V_ = 64, E_ = 128, H_ = 512, LAT_ = 256;
constexpr int H3 = 1536;  // 3*H

DI short f2b(float f) {
  union { __hip_bfloat16 h; short s; } u;
  u.h = __float2bfloat16(f);
  return u.s;
}
DI float b2f(short s) {
  union { unsigned u; float f; } x;
  x.u = (unsigned)(unsigned short)s << 16;
  return x.f;
}
DI float sigm(float x) { return 1.f / (1.f + __expf(-x)); }
DI float tanh_f(float x) {
  x = fminf(15.f, fmaxf(-15.f, x));
  float e = __expf(2.f * x);
  return (e - 1.f) / (e + 1.f);
}
DI float gru_one(float xr, float xz, float xn, float hr, float hz, float hn, float hp) {
  float r = sigm(xr + hr);
  float u = sigm(xz + hz);
  float nn = tanh_f(xn + r * hn);
  return (1.f - u) * nn + u * hp;
}

// ======== register staging: global -> regs -> swizzled ds_write ========
template <int ROWS, int BK, int NV>
DI void rs_load(const short* __restrict__ G, int row0, int K, int kk, bf16x8 (&v)[NV]) {
  constexpr int SLOTS = BK / 8;
  constexpr int RPP = 2048 / BK;
  static_assert(NV == ROWS / RPP, "NV mismatch");
  const int tid = threadIdx.x;
  const int rl = tid / SLOTS, sl = tid % SLOTS;
#pragma unroll
  for (int p = 0; p < NV; ++p)
    v[p] = *(const bf16x8*)(G + (size_t)(row0 + p * RPP + rl) * K + kk + sl * 8);
}
template <int ROWS, int BK, int NV>
DI void rs_write(char* __restrict__ lds, bf16x8 (&v)[NV]) {
  constexpr int SLOTS = BK / 8;
  constexpr int RPP = 2048 / BK;
  const int tid = threadIdx.x;
  const int rl = tid / SLOTS, sl = tid % SLOTS;
#pragma unroll
  for (int p = 0; p < NV; ++p) {
    int row = p * RPP + rl;
    *(bf16x8*)(lds + row * (SLOTS * 16) + ((sl ^ (row & (SLOTS - 1))) * 16)) = v[p];
  }
}
template <int BK>
DI bf16x8 fragL(const char* __restrict__ lds, int row, int kk) {
  return *(const bf16x8*)(lds + row * (BK * 2) + ((kk << 1) ^ ((row & (BK / 8 - 1)) << 4)));
}

// ======== double-buffered 64x128 GEMM: C = A[64x512] @ W[128x512]^T + bias ========
// LDS: As0@0, As1@8K, Bs0@16K, Bs1@32K  (48KB). One barrier per 64-K chunk.
DI void gemm_64x128_db(const short* __restrict__ A, const short* __restrict__ Bw,
                       const float* __restrict__ bias, short* __restrict__ C,
                       int arow, int bcol, char* lds) {
  char* As[2] = {lds, lds + 8192};
  char* Bs[2] = {lds + 16384, lds + 32768};
  const int tid = threadIdx.x, lane = tid & 63, wid = tid >> 6;
  const int wm = wid >> 1, wn = wid & 1;
  const int r = lane & 15, ko = (lane >> 4) * 8;
  bf16x8 va[2], vb[4];
  f32x4 acc[2][4] = {};
  rs_load<64, 64, 2>(A, arow, H_, 0, va);
  rs_load<128, 64, 4>(Bw, bcol, H_, 0, vb);
  rs_write<64, 64, 2>(As[0], va);
  rs_write<128, 64, 4>(Bs[0], vb);
  __syncthreads();
  int cur = 0;
  for (int c = 0; c < 8; ++c) {
    if (c < 7) {
      rs_load<64, 64, 2>(A, arow, H_, (c + 1) * 64, va);
      rs_load<128, 64, 4>(Bw, bcol, H_, (c + 1) * 64, vb);
    }
#pragma unroll
    for (int kh = 0; kh < 2; ++kh) {
      const int kkk = kh * 32 + ko;
      bf16x8 a[2], b[4];
#pragma unroll
      for (int i = 0; i < 2; ++i) a[i] = fragL<64>(As[cur], wm * 32 + i * 16 + r, kkk);
#pragma unroll
      for (int j = 0; j < 4; ++j) b[j] = fragL<64>(Bs[cur], wn * 64 + j * 16 + r, kkk);
#pragma unroll
      for (int i = 0; i < 2; ++i)
#pragma unroll
        for (int j = 0; j < 4; ++j)
          acc[i][j] = __builtin_amdgcn_mfma_f32_16x16x32_bf16(a[i], b[j], acc[i][j], 0, 0, 0);
    }
    if (c < 7) {  // write next chunk into the OTHER buffer (no read/write overlap)
      rs_write<64, 64, 2>(As[cur ^ 1], va);
      rs_write<128, 64, 4>(Bs[cur ^ 1], vb);
    }
    __syncthreads();
    cur ^= 1;
  }
  const int r0 = (lane >> 4) * 4, c0 = lane & 15;
#pragma unroll
  for (int i = 0; i < 2; ++i)
#pragma unroll
    for (int j = 0; j < 4; ++j) {
      int col = bcol + wn * 64 + j * 16 + c0;
      float bv = bias[col];
#pragma unroll
      for (int rr = 0; rr < 4; ++rr)
        C[(size_t)(arow + wm * 32 + i * 16 + r0 + rr) * H3 + col] = f2b(acc[i][j][rr] + bv);
    }
}

// ---- direct-global fragment GEMM (prep only)
template <int MI, int NJ>
DI void gemm_wave_global(const short* __restrict__ A, const short* __restrict__ B,
                         const int K, const int arow, const int bcol,
                         f32x4 (&acc)[MI][NJ]) {
  const int lane = threadIdx.x & 63;
  const int r = lane & 15, ko = (lane >> 4) * 8;
  const short* Ap = A + (size_t)(arow + r) * K + ko;
  const short* Bp = B + (size_t)(bcol + r) * K + ko;
  for (int kk = 0; kk < K; kk += 32) {
    bf16x8 a[MI], b[NJ];
#pragma unroll
    for (int i = 0; i < MI; ++i) a[i] = *(const bf16x8*)(Ap + (size_t)i * 16 * K + kk);
#pragma unroll
    for (int j = 0; j < NJ; ++j) b[j] = *(const bf16x8*)(Bp + (size_t)j * 16 * K + kk);
#pragma unroll
    for (int i = 0; i < MI; ++i)
#pragma unroll
      for (int j = 0; j < NJ; ++j)
        acc[i][j] = __builtin_amdgcn_mfma_f32_16x16x32_bf16(a[i], b[j], acc[i][j], 0, 0, 0);
  }
}
template <int MI, int NJ>
DI void epi_store_bf16(short* __restrict__ C, const float* __restrict__ bias,
                       const int N, const int arow, const int bcol, f32x4 (&acc)[MI][NJ]) {
  const int lane = threadIdx.x & 63;
  const int r0 = (lane >> 4) * 4, c0 = lane & 15;
#pragma unroll
  for (int i = 0; i < MI; ++i)
#pragma unroll
    for (int j = 0; j < NJ; ++j) {
      int col = bcol + j * 16 + c0;
      float bv = bias[col];
#pragma unroll
      for (int rr = 0; rr < 4; ++rr)
        C[(size_t)(arow + i * 16 + r0 + rr) * N + col] = f2b(acc[i][j][rr] + bv);
    }
}

// ======== shared arg bundle ========
struct SArgs {
  const short* zgx; const short* egx; const int* target;
  float* h0f0; float* h0f1; short* h0b0; short* h0b1;
  float* h1f; short* h1b;
  short* gh0; short* gh1; short* gx1;
  const short* Wb_hh0; const float* b_hh0;
  const short* Wb_ih1; const float* b_ih1;
  const short* Wb_hh1; const float* b_hh1;
  const short* Wb_out; const float* fc_out_b;
  float* out;
};

// ---- pw1(t-1)+logits unit: 16 rows
DI void unit_pw1(const SArgs& a, int v, int t, char* smem) {
  short* sh = (short*)smem;
  const int row0 = v * 16;
  const int tid = threadIdx.x;
  const int tlog = t - 1;
#pragma unroll 1
  for (int c = 0; c < 4; ++c) {
    int f = c * 2048 + tid * 8;
    int rl = f >> 9, j = f & 511;
    int row = row0 + rl;
    const short* gx = a.gx1 + (size_t)row * H3 + j;
    const short* gh = a.gh1 + (size_t)row * H3 + j;
    float* hf = a.h1f + (size_t)row * H_ + j;
    bf16x8 xr = *(const bf16x8*)(gx);
    bf16x8 xz = *(const bf16x8*)(gx + H_);
    bf16x8 xn = *(const bf16x8*)(gx + 2 * H_);
    bf16x8 hr = *(const bf16x8*)(gh);
    bf16x8 hz = *(const bf16x8*)(gh + H_);
    bf16x8 hn = *(const bf16x8*)(gh + 2 * H_);
    float4 hp0 = *(const float4*)(hf);
    float4 hp1 = *(const float4*)(hf + 4);
    float hp[8] = {hp0.x, hp0.y, hp0.z, hp0.w, hp1.x, hp1.y, hp1.z, hp1.w};
    float hv[8];
    bf16x8 ov;
#pragma unroll
    for (int e = 0; e < 8; ++e) {
      hv[e] = gru_one(b2f(xr[e]), b2f(xz[e]), b2f(xn[e]),
                      b2f(hr[e]), b2f(hz[e]), b2f(hn[e]), hp[e]);
      ov[e] = f2b(hv[e]);
    }
    *(float4*)(hf) = make_float4(hv[0], hv[1], hv[2], hv[3]);
    *(float4*)(hf + 4) = make_float4(hv[4], hv[5], hv[6], hv[7]);
    *(bf16x8*)(a.h1b + (size_t)row * H_ + j) = ov;
    *(bf16x8*)(&sh[rl * 520 + j]) = ov;
  }
  __syncthreads();
  const int lane = tid & 63, w = tid >> 6;
  const int c0 = lane & 15, ko = (lane >> 4) * 8;
  f32x4 acc = {};
  const short* wb = a.Wb_out + (size_t)(w * 16 + c0) * H_ + ko;
  const short* ap = &sh[c0 * 520 + ko];
#pragma unroll
  for (int m = 0; m < 16; ++m) {
    bf16x8 av = *(const bf16x8*)(ap + m * 32);
    bf16x8 bw = *(const bf16x8*)(wb + m * 32);
    acc = __builtin_amdgcn_mfma_f32_16x16x32_bf16(av, bw, acc, 0, 0, 0);
  }
  const int r0 = (lane >> 4) * 4;
  const int col = w * 16 + c0;
  const float bv = a.fc_out_b[col];
#pragma unroll
  for (int rr = 0; rr < 4; ++rr) {
    int brow = row0 + r0 + rr;
    a.out[((size_t)brow * T_ + tlog) * V_ + col] = acc[rr] + bv;
  }
}

// ---- pw0(t) + gx1(t) unit: 32 rows x 256 weight cols (nt in [0,6))
DI void unit_pw0gx1(const SArgs& a, int v, int t, char* smem) {
  const int p = t & 1;
  const float* h0f_prev = p ? a.h0f1 : a.h0f0;
  float* h0f_new = p ? a.h0f0 : a.h0f1;
  short* h0b_new = p ? a.h0b0 : a.h0b1;
  const int mt = v / 6, nt = v % 6;
  const int mbase = mt * 32, nb = nt * 256;
  const int tid = threadIdx.x;
  char* hns = smem;          // 32 x 512 bf16, swizzled (32KB)
  char* Bs = smem + 32768;   // 256 x 32 bf16 chunk (16KB)
  bf16x8 vb[4];
  rs_load<256, 32, 4>(a.Wb_ih1, nb, H_, 0, vb);  // chunk0 early
#pragma unroll 1
  for (int c = 0; c < 8; ++c) {
    int f = c * 2048 + tid * 8;
    int rl = f >> 9, j = f & 511;
    int row = mbase + rl;
    int tok = (t == 0) ? 1 : a.target[(size_t)row * T_ + (t - 1)];
    const short* zg = a.zgx + (size_t)row * H3 + j;
    const short* eg = a.egx + (size_t)tok * H3 + j;
    const short* gh = a.gh0 + (size_t)row * H3 + j;
    const float* hf = h0f_prev + (size_t)row * H_ + j;
    bf16x8 zr = *(const bf16x8*)(zg);
    bf16x8 zz = *(const bf16x8*)(zg + H_);
    bf16x8 zn = *(const bf16x8*)(zg + 2 * H_);
    bf16x8 er = *(const bf16x8*)(eg);
    bf16x8 ez = *(const bf16x8*)(eg + H_);
    bf16x8 en = *(const bf16x8*)(eg + 2 * H_);
    bf16x8 hr = *(const bf16x8*)(gh);
    bf16x8 hz = *(const bf16x8*)(gh + H_);
    bf16x8 hn = *(const bf16x8*)(gh + 2 * H_);
    float4 hp0 = *(const float4*)(hf);
    float4 hp1 = *(const float4*)(hf + 4);
    float hp[8] = {hp0.x, hp0.y, hp0.z, hp0.w, hp1.x, hp1.y, hp1.z, hp1.w};
    float hv[8];
    bf16x8 ov;
#pragma unroll
    for (int e = 0; e < 8; ++e) {
      hv[e] = gru_one(b2f(zr[e]) + b2f(er[e]), b2f(zz[e]) + b2f(ez[e]),
                      b2f(zn[e]) + b2f(en[e]),
                      b2f(hr[e]), b2f(hz[e]), b2f(hn[e]), hp[e]);
      ov[e] = f2b(hv[e]);
    }
    *(bf16x8*)(hns + (rl << 10) + ((j << 1) ^ ((rl & 7) << 4))) = ov;
    if (nt == 0) {
      float* ho = h0f_new + (size_t)row * H_ + j;
      *(float4*)(ho) = make_float4(hv[0], hv[1], hv[2], hv[3]);
      *(float4*)(ho + 4) = make_float4(hv[4], hv[5], hv[6], hv[7]);
      *(bf16x8*)(h0b_new + (size_t)row * H_ + j) = ov;
    }
  }
  __syncthreads();
  rs_write<256, 32, 4>(Bs, vb);
  __syncthreads();
  const int lane = tid & 63, wid = tid >> 6;
  const int r = lane & 15, ko = (lane >> 4) * 8;
  f32x4 acc[2][4] = {};
  for (int c = 0; c < 16; ++c) {
    if (c < 15) rs_load<256, 32, 4>(a.Wb_ih1, nb, H_, (c + 1) * 32, vb);
    bf16x8 av[2], bv2[4];
#pragma unroll
    for (int i = 0; i < 2; ++i) {
      int row = i * 16 + r;
      av[i] = *(const bf16x8*)(hns + (row << 10) + ((((c * 32 + ko) << 1)) ^ ((row & 7) << 4)));
    }
#pragma unroll
    for (int j = 0; j < 4; ++j) bv2[j] = fragL<32>(Bs, wid * 64 + j * 16 + r, ko);
#pragma unroll
    for (int i = 0; i < 2; ++i)
#pragma unroll
      for (int j = 0; j < 4; ++j)
        acc[i][j] = __builtin_amdgcn_mfma_f32_16x16x32_bf16(av[i], bv2[j], acc[i][j], 0, 0, 0);
    __syncthreads();
    if (c < 15) {
      rs_write<256, 32, 4>(Bs, vb);
      __syncthreads();
    }
  }
  const int r0 = (lane >> 4) * 4, c0 = lane & 15;
#pragma unroll
  for (int i = 0; i < 2; ++i)
#pragma unroll
    for (int j = 0; j < 4; ++j) {
      int col = nb + wid * 64 + j * 16 + c0;
      float bvv = a.b_ih1[col];
#pragma unroll
      for (int rr = 0; rr < 4; ++rr)
        a.gx1[(size_t)(mbase + i * 16 + r0 + rr) * H3 + col] = f2b(acc[i][j][rr] + bvv);
    }
}

// ---- phases (grid-stride over units; uniform control flow per block)
DI void phaseA(const SArgs& a, int t, char* smem, int bid, int nbk) {
  const short* h0b_cur = (t & 1) ? a.h0b1 : a.h0b0;
  for (int u = bid; u < 512; u += nbk) {
    if (u < 384) {
      if (t < T_)
        gemm_64x128_db(h0b_cur, a.Wb_hh0, a.b_hh0, a.gh0, (u / 12) * 64, (u % 12) * 128, smem);
    } else if (t >= 1) {
      unit_pw1(a, u - 384, t, smem);
    }
    __syncthreads();
  }
}
DI void phaseB(const SArgs& a, int t, char* smem, int bid, int nbk) {
  for (int u = bid; u < 768; u += nbk) {
    if (u < 384)
      gemm_64x128_db(a.h1b, a.Wb_hh1, a.b_hh1, a.gh1, (u / 12) * 64, (u % 12) * 128, smem);
    else
      unit_pw0gx1(a, u - 384, t, smem);
    __syncthreads();
  }
}

// ---- persistent cooperative kernel: whole T loop, 2 grid syncs per step
__global__ __launch_bounds__(256, 3) void k_persist(SArgs a) {
  extern __shared__ char smem[];
  cg::grid_group g = cg::this_grid();
  const int bid = blockIdx.x, nbk = gridDim.x;
  for (int t = 0; t < T_; ++t) {
    phaseA(a, t, smem, bid, nbk);
    g.sync();
    phaseB(a, t, smem, bid, nbk);
    g.sync();
  }
  phaseA(a, T_, smem, bid, nbk);  // final pw1+logits for t=T-1
}

// ---- fallback (non-cooperative) kernels, identical math
__global__ __launch_bounds__(256) void k_phA(SArgs a, int t) {
  extern __shared__ char smem[];
  phaseA(a, t, smem, blockIdx.x, gridDim.x);
}
__global__ __launch_bounds__(256) void k_phB(SArgs a, int t) {
  extern __shared__ char smem[];
  phaseB(a, t, smem, blockIdx.x, gridDim.x);
}

// ================= prep kernels =================
__global__ __launch_bounds__(256) void k_prep0(
    const float* __restrict__ W_hh0, const float* __restrict__ W_ih1,
    const float* __restrict__ W_hh1, const float* __restrict__ fc_out_w,
    const float* __restrict__ W_ih0, const float* __restrict__ fc_hidden_w,
    const float* __restrict__ z,
    short* Wb_hh0, short* Wb_ih1, short* Wb_hh1, short* Wb_out,
    short* Wb_ih0z, short* Wb_fch, short* z_b) {
  const int n1 = H3 * H_;
  const int n2 = V_ * H_;
  const int n3 = H3 * LAT_;
  const int n4 = (2 * H_) * LAT_;
  const int n5 = B_ * LAT_;
  const int total = n1 * 3 + n2 + n3 + n4 + n5;
  for (int i = blockIdx.x * blockDim.x + threadIdx.x; i < total;
       i += gridDim.x * blockDim.x) {
    int idx = i;
    if (idx < n1) { Wb_hh0[idx] = f2b(W_hh0[idx]); continue; }
    idx -= n1;
    if (idx < n1) { Wb_ih1[idx] = f2b(W_ih1[idx]); continue; }
    idx -= n1;
    if (idx < n1) { Wb_hh1[idx] = f2b(W_hh1[idx]); continue; }
    idx -= n1;
    if (idx < n2) { Wb_out[idx] = f2b(fc_out_w[idx]); continue; }
    idx -= n2;
    if (idx < n3) {
      int n = idx >> 8, k = idx & 255;
      Wb_ih0z[idx] = f2b(W_ih0[(size_t)n * (E_ + LAT_) + E_ + k]);
      continue;
    }
    idx -= n3;
    if (idx < n4) { Wb_fch[idx] = f2b(fc_hidden_w[idx]); continue; }
    idx -= n4;
    z_b[idx] = f2b(z[idx]);
  }
}

__global__ __launch_bounds__(256) void k_prep_emb(const float* __restrict__ embed,
                                                  const float* __restrict__ W_ih0,
                                                  short* __restrict__ egx) {
  __shared__ float er[E_];
  int v = blockIdx.x;
  for (int e = threadIdx.x; e < E_; e += blockDim.x) er[e] = embed[(size_t)v * E_ + e];
  __syncthreads();
  for (int n = threadIdx.x; n < H3; n += blockDim.x) {
    const float* w = W_ih0 + (size_t)n * (E_ + LAT_);
    float acc = 0.f;
#pragma unroll 8
    for (int e = 0; e < E_; ++e) acc += er[e] * w[e];
    egx[(size_t)v * H3 + n] = f2b(acc);
  }
}

__global__ __launch_bounds__(256) void k_prep1(
    const short* __restrict__ z_b, const short* __restrict__ Wb_ih0z,
    const short* __restrict__ Wb_fch, const float* __restrict__ b_ih0,
    const float* __restrict__ fc_hidden_b,
    short* zgx, float* h0f, float* h1f, short* h0b, short* h1b) {
  const int bid = blockIdx.x;
  const int mtile = bid / 20, ntile = bid % 20;
  const int tid = threadIdx.x, lane = tid & 63, wid = tid >> 6;
  const int wm = wid >> 1, wn = wid & 1;
  const int arow = mtile * 128 + wm * 64;
  f32x4 acc[4][4] = {};
  if (ntile < 12) {
    int bcol = ntile * 128 + wn * 64;
    gemm_wave_global<4, 4>(z_b, Wb_ih0z, LAT_, arow, bcol, acc);
    epi_store_bf16<4, 4>(zgx, b_ih0, H3, arow, bcol, acc);
  } else {
    int bcol = (ntile - 12) * 128 + wn * 64;
    gemm_wave_global<4, 4>(z_b, Wb_fch, LAT_, arow, bcol, acc);
    const int r0 = (lane >> 4) * 4, c0 = lane & 15;
#pragma unroll
    for (int i = 0; i < 4; ++i)
#pragma unroll
      for (int j = 0; j < 4; ++j) {
        int col = bcol + j * 16 + c0;
        float bv = fc_hidden_b[col];
#pragma unroll
        for (int rr = 0; rr < 4; ++rr) {
          int row = arow + i * 16 + r0 + rr;
          float v = acc[i][j][rr] + bv;
          if (col < H_) {
            h0f[(size_t)row * H_ + col] = v;
            h0b[(size_t)row * H_ + col] = f2b(v);
          } else {
            h1f[(size_t)row * H_ + (col - H_)] = v;
            h1b[(size_t)row * H_ + (col - H_)] = f2b(v);
          }
        }
      }
  }
}

extern "C" void kernel_launch(void* const* d_in, const int* in_sizes, int n_in,
                              void* d_out, int out_size, void* d_ws, size_t ws_size,
                              hipStream_t stream) {
  const float* z           = (const float*)d_in[0];
  const int*   target      = (const int*)d_in[1];
  const float* embed       = (const float*)d_in[2];
  const float* fc_hidden_w = (const float*)d_in[3];
  const float* fc_hidden_b = (const float*)d_in[4];
  const float* W_ih0       = (const float*)d_in[5];
  const float* W_hh0       = (const float*)d_in[6];
  const float* b_ih0       = (const float*)d_in[7];
  const float* b_hh0       = (const float*)d_in[8];
  const float* W_ih1       = (const float*)d_in[9];
  const float* W_hh1       = (const float*)d_in[10];
  const float* b_ih1       = (const float*)d_in[11];
  const float* b_hh1       = (const float*)d_in[12];
  const float* fc_out_w    = (const float*)d_in[13];
  const float* fc_out_b    = (const float*)d_in[14];
  float* out = (float*)d_out;

  char* ws = (char*)d_ws;
  size_t off = 0;
  auto alloc = [&](size_t bytes) -> void* {
    off = (off + 255) & ~(size_t)255;
    void* p = ws + off;
    off += bytes;
    return p;
  };
  float* h0f0   = (float*)alloc((size_t)B_ * H_ * 4);
  float* h0f1   = (float*)alloc((size_t)B_ * H_ * 4);
  float* h1f    = (float*)alloc((size_t)B_ * H_ * 4);
  short* h0b0   = (short*)alloc((size_t)B_ * H_ * 2);
  short* h0b1   = (short*)alloc((size_t)B_ * H_ * 2);
  short* h1b    = (short*)alloc((size_t)B_ * H_ * 2);
  short* gh0    = (short*)alloc((size_t)B_ * H3 * 2);
  short* gh1    = (short*)alloc((size_t)B_ * H3 * 2);
  short* gx1    = (short*)alloc((size_t)B_ * H3 * 2);
  short* zgx    = (short*)alloc((size_t)B_ * H3 * 2);
  short* egx    = (short*)alloc((size_t)V_ * H3 * 2);
  short* Wb_hh0 = (short*)alloc((size_t)H3 * H_ * 2);
  short* Wb_ih1 = (short*)alloc((size_t)H3 * H_ * 2);
  short* Wb_hh1 = (short*)alloc((size_t)H3 * H_ * 2);
  short* Wb_out = (short*)alloc((size_t)V_ * H_ * 2);
  short* Wb_ih0z= (short*)alloc((size_t)H3 * LAT_ * 2);
  short* Wb_fch = (short*)alloc((size_t)2 * H_ * LAT_ * 2);
  short* z_b    = (short*)alloc((size_t)B_ * LAT_ * 2);
  if (off > ws_size) return;

  k_prep0<<<2048, 256, 0, stream>>>(W_hh0, W_ih1, W_hh1, fc_out_w, W_ih0, fc_hidden_w,
                                    z, Wb_hh0, Wb_ih1, Wb_hh1, Wb_out, Wb_ih0z, Wb_fch, z_b);
  k_prep_emb<<<64, 256, 0, stream>>>(embed, W_ih0, egx);
  k_prep1<<<320, 256, 0, stream>>>(z_b, Wb_ih0z, Wb_fch, b_ih0, fc_hidden_b,
                                   zgx, h0f0, h1f, h0b0, h1b);

  SArgs a;
  a.zgx = zgx; a.egx = egx; a.target = target;
  a.h0f0 = h0f0; a.h0f1 = h0f1; a.h0b0 = h0b0; a.h0b1 = h0b1;
  a.h1f = h1f; a.h1b = h1b;
  a.gh0 = gh0; a.gh1 = gh1; a.gx1 = gx1;
  a.Wb_hh0 = Wb_hh0; a.b_hh0 = b_hh0;
  a.Wb_ih1 = Wb_ih1; a.b_ih1 = b_ih1;
  a.Wb_hh1 = Wb_hh1; a.b_hh1 = b_hh1;
  a.Wb_out = Wb_out; a.fc_out_b = fc_out_b;
  a.out = out;

  void* kargs[] = {(void*)&a};
  hipError_t ce = hipLaunchCooperativeKernel((const void*)k_persist, dim3(768), dim3(256),
                                             kargs, 49152, stream);
  if (ce != hipSuccess) {
    (void)hipGetLastError();  // clear sticky error, use fallback schedule
    for (int t = 0; t < T_; ++t) {
      k_phA<<<512, 256, 49152, stream>>>(a, t);
      k_phB<<<768, 256, 49152, stream>>>(a, t);
    }
    k_phA<<<128, 256, 49152, stream>>>(a, T_);
  }
}

// Round 6
// 24516.263 us; speedup vs baseline: 1.2111x; 1.2111x over previous
//
#include <hip/hip_runtime.h>
#include <hip/hip_bf16.h>

#define DI __device__ __forceinline__

typedef short bf16x8 __attribute__((ext_vector_type(8)));
typedef float f32x4 __attribute__((ext_vector_type(4)));

constexpr int B_ = 2048, T_ = 120, V_ = 64, E_ = 128, H_ = 512, LAT_ = 256;
constexpr int H3 = 1536;  // 3*H

DI short f2b(float f) {
  union { __hip_bfloat16 h; short s; } u;
  u.h = __float2bfloat16(f);
  return u.s;
}
DI float b2f(short s) {
  union { unsigned u; float f; } x;
  x.u = (unsigned)(unsigned short)s << 16;
  return x.f;
}
DI float sigm(float x) { return 1.f / (1.f + __expf(-x)); }
DI float tanh_f(float x) {
  x = fminf(15.f, fmaxf(-15.f, x));
  float e = __expf(2.f * x);
  return (e - 1.f) / (e + 1.f);
}
DI float gru_one(float xr, float xz, float xn, float hr, float hz, float hn, float hp) {
  float r = sigm(xr + hr);
  float u = sigm(xz + hz);
  float nn = tanh_f(xn + r * hn);
  return (1.f - u) * nn + u * hp;
}

// ======== register staging: global -> regs -> swizzled ds_write (256 threads) ========
template <int ROWS, int BK, int NV>
DI void rs_load(const short* __restrict__ G, int row0, int K, int kk, bf16x8 (&v)[NV]) {
  constexpr int SLOTS = BK / 8;
  constexpr int RPP = 2048 / BK;
  static_assert(NV == ROWS / RPP, "NV mismatch");
  const int tid = threadIdx.x;
  const int rl = tid / SLOTS, sl = tid % SLOTS;
#pragma unroll
  for (int p = 0; p < NV; ++p)
    v[p] = *(const bf16x8*)(G + (size_t)(row0 + p * RPP + rl) * K + kk + sl * 8);
}
template <int ROWS, int BK, int NV>
DI void rs_write(char* __restrict__ lds, bf16x8 (&v)[NV]) {
  constexpr int SLOTS = BK / 8;
  constexpr int RPP = 2048 / BK;
  const int tid = threadIdx.x;
  const int rl = tid / SLOTS, sl = tid % SLOTS;
#pragma unroll
  for (int p = 0; p < NV; ++p) {
    int row = p * RPP + rl;
    *(bf16x8*)(lds + row * (SLOTS * 16) + ((sl ^ (row & (SLOTS - 1))) * 16)) = v[p];
  }
}
template <int BK>
DI bf16x8 fragL(const char* __restrict__ lds, int row, int kk) {
  return *(const bf16x8*)(lds + row * (BK * 2) + ((kk << 1) ^ ((row & (BK / 8 - 1)) << 4)));
}
// hb tile [32][512] bf16, row stride 1024B, 16B-slot XOR swizzle by (row&7)
DI bf16x8 hb_frag(const char* __restrict__ hb, int row, int kel) {
  return *(const bf16x8*)(hb + row * 1024 + ((kel << 1) ^ ((row & 7) << 4)));
}

// ================= persistent row-band kernel =================
struct RArgs {
  const short* zgx; const short* egx; const int* target;
  float* h0f; float* h1f; short* h0b; short* h1b;
  const short* Wb_hh0; const float* b_hh0;
  const short* Wb_ih1; const float* b_ih1;
  const short* Wb_hh1; const float* b_hh1;
  const short* Wb_out; const float* fc_out_b;
  float* out;
};

DI void reload_hb(char* __restrict__ hb, const short* __restrict__ hbg, int row0) {
  const int tid = threadIdx.x;
#pragma unroll 1
  for (int idx = tid; idx < 2048; idx += 256) {
    int row = idx >> 6, sl = idx & 63;
    bf16x8 v = *(const bf16x8*)(hbg + (size_t)(row0 + row) * H_ + sl * 8);
    *(bf16x8*)(hb + row * 1024 + ((sl << 4) ^ ((row & 7) << 4))) = v;
  }
}

// C[32 x 3x(128-chunk)] += hb[32x512] @ W[rows g*512+c*128.. , 512]^T
// 4 waves: wave w owns cols w*32 + k*16 within each gate strip. BK=64 dbuf staging.
DI void gemm_chunk(const char* __restrict__ hbA, const short* __restrict__ W, int c,
                   char* ws0, char* ws1, int w, int q, int c0,
                   f32x4 (&acc)[2][3][2]) {
  bf16x8 sv[3][4];
#pragma unroll
  for (int g = 0; g < 3; ++g) rs_load<128, 64, 4>(W, g * 512 + c * 128, H_, 0, sv[g]);
#pragma unroll
  for (int g = 0; g < 3; ++g) rs_write<128, 64, 4>(ws0 + g * 16384, sv[g]);
  __syncthreads();
  char* bufs[2] = {ws0, ws1};
#pragma unroll 1
  for (int bk = 0; bk < 8; ++bk) {
    if (bk < 7) {
#pragma unroll
      for (int g = 0; g < 3; ++g)
        rs_load<128, 64, 4>(W, g * 512 + c * 128, H_, (bk + 1) * 64, sv[g]);
    }
    const char* cb = bufs[bk & 1];
#pragma unroll
    for (int kh = 0; kh < 2; ++kh) {
      const int kel = bk * 64 + kh * 32 + q * 8;
      bf16x8 af[2];
#pragma unroll
      for (int i = 0; i < 2; ++i) af[i] = hb_frag(hbA, i * 16 + c0, kel);
#pragma unroll
      for (int g = 0; g < 3; ++g)
#pragma unroll
        for (int k = 0; k < 2; ++k) {
          bf16x8 bf = fragL<64>(cb + g * 16384, w * 32 + k * 16 + c0, kh * 32 + q * 8);
#pragma unroll
          for (int i = 0; i < 2; ++i)
            acc[i][g][k] = __builtin_amdgcn_mfma_f32_16x16x32_bf16(af[i], bf, acc[i][g][k], 0, 0, 0);
        }
    }
    if (bk < 7) {
#pragma unroll
      for (int g = 0; g < 3; ++g) rs_write<128, 64, 4>(bufs[(bk + 1) & 1] + g * 16384, sv[g]);
    }
    __syncthreads();
  }
}

__global__ __launch_bounds__(256, 1) void k_row(RArgs a) {
  extern __shared__ char smem[];
  char* hb0 = smem;
  char* hb1 = smem + 32768;
  char* ws0 = smem + 65536;
  char* ws1 = smem + 114688;
  const int tid = threadIdx.x, lane = tid & 63, w = tid >> 6;
  const int q = lane >> 4, c0 = lane & 15;
  const int row0 = blockIdx.x * 32;
  reload_hb(hb0, a.h0b, row0);
  reload_hb(hb1, a.h1b, row0);
  __syncthreads();
#pragma unroll 1
  for (int t = 0; t < T_; ++t) {
    // ---- phase 1: gh0 chunks + pw0 (h0n -> global h0f/h0b)
#pragma unroll 1
    for (int c = 0; c < 4; ++c) {
      f32x4 acc[2][3][2] = {};
      gemm_chunk(hb0, a.Wb_hh0, c, ws0, ws1, w, q, c0, acc);
#pragma unroll
      for (int i = 0; i < 2; ++i)
#pragma unroll
        for (int k = 0; k < 2; ++k) {
          const int j = c * 128 + w * 32 + k * 16 + c0;
          const float bR = a.b_hh0[j], bZ = a.b_hh0[512 + j], bN = a.b_hh0[1024 + j];
#pragma unroll
          for (int rr = 0; rr < 4; ++rr) {
            const int rl = i * 16 + q * 4 + rr, rg = row0 + rl;
            const int tok = (t == 0) ? 1 : a.target[(size_t)rg * T_ + (t - 1)];
            const short* zp = a.zgx + (size_t)rg * H3 + j;
            const short* ep = a.egx + (size_t)tok * H3 + j;
            float gxr = b2f(zp[0]) + b2f(ep[0]);
            float gxz = b2f(zp[512]) + b2f(ep[512]);
            float gxn = b2f(zp[1024]) + b2f(ep[1024]);
            float hp = a.h0f[(size_t)rg * H_ + j];
            float h = gru_one(gxr, gxz, gxn, acc[i][0][k][rr] + bR,
                              acc[i][1][k][rr] + bZ, acc[i][2][k][rr] + bN, hp);
            a.h0f[(size_t)rg * H_ + j] = h;
            a.h0b[(size_t)rg * H_ + j] = f2b(h);
          }
        }
    }
    __syncthreads();          // all hb0 A-reads + pw0 global stores done
    reload_hb(hb0, a.h0b, row0);
    __syncthreads();          // hb0 = h0(t)
    // ---- phase 2: gx1 + gh1 chunks + pw1 (h1n -> global h1f/h1b)
#pragma unroll 1
    for (int c = 0; c < 4; ++c) {
      f32x4 agx[2][3][2] = {};
      gemm_chunk(hb0, a.Wb_ih1, c, ws0, ws1, w, q, c0, agx);
      f32x4 agh[2][3][2] = {};
      gemm_chunk(hb1, a.Wb_hh1, c, ws0, ws1, w, q, c0, agh);
#pragma unroll
      for (int i = 0; i < 2; ++i)
#pragma unroll
        for (int k = 0; k < 2; ++k) {
          const int j = c * 128 + w * 32 + k * 16 + c0;
          const float xR = a.b_ih1[j], xZ = a.b_ih1[512 + j], xN = a.b_ih1[1024 + j];
          const float hR = a.b_hh1[j], hZ = a.b_hh1[512 + j], hN = a.b_hh1[1024 + j];
#pragma unroll
          for (int rr = 0; rr < 4; ++rr) {
            const int rl = i * 16 + q * 4 + rr, rg = row0 + rl;
            float hp = a.h1f[(size_t)rg * H_ + j];
            float h = gru_one(agx[i][0][k][rr] + xR, agx[i][1][k][rr] + xZ,
                              agx[i][2][k][rr] + xN, agh[i][0][k][rr] + hR,
                              agh[i][1][k][rr] + hZ, agh[i][2][k][rr] + hN, hp);
            a.h1f[(size_t)rg * H_ + j] = h;
            a.h1b[(size_t)rg * H_ + j] = f2b(h);
          }
        }
    }
    __syncthreads();
    reload_hb(hb1, a.h1b, row0);
    __syncthreads();          // hb1 = h1(t)
    // ---- logits(t): 32x64 = hb1 @ Wout^T
    f32x4 lacc[2] = {};
#pragma unroll 1
    for (int ks = 0; ks < 16; ++ks) {
      const int kel = ks * 32 + q * 8;
      bf16x8 b = *(const bf16x8*)(a.Wb_out + (size_t)(w * 16 + c0) * H_ + kel);
#pragma unroll
      for (int i = 0; i < 2; ++i) {
        bf16x8 af = hb_frag(hb1, i * 16 + c0, kel);
        lacc[i] = __builtin_amdgcn_mfma_f32_16x16x32_bf16(af, b, lacc[i], 0, 0, 0);
      }
    }
    const float bo = a.fc_out_b[w * 16 + c0];
#pragma unroll
    for (int i = 0; i < 2; ++i)
#pragma unroll
      for (int rr = 0; rr < 4; ++rr)
        a.out[(size_t)(row0 + i * 16 + q * 4 + rr) * (T_ * V_) + t * V_ + w * 16 + c0] =
            lacc[i][rr] + bo;
  }
}

// ================= fallback (R3/R4-proven multi-launch path) =================
DI void gemm_64x128_db(const short* __restrict__ A, const short* __restrict__ Bw,
                       const float* __restrict__ bias, short* __restrict__ C,
                       int arow, int bcol, char* lds) {
  char* As[2] = {lds, lds + 8192};
  char* Bs[2] = {lds + 16384, lds + 32768};
  const int tid = threadIdx.x, lane = tid & 63, wid = tid >> 6;
  const int wm = wid >> 1, wn = wid & 1;
  const int r = lane & 15, ko = (lane >> 4) * 8;
  bf16x8 va[2], vb[4];
  f32x4 acc[2][4] = {};
  rs_load<64, 64, 2>(A, arow, H_, 0, va);
  rs_load<128, 64, 4>(Bw, bcol, H_, 0, vb);
  rs_write<64, 64, 2>(As[0], va);
  rs_write<128, 64, 4>(Bs[0], vb);
  __syncthreads();
  int cur = 0;
  for (int c = 0; c < 8; ++c) {
    if (c < 7) {
      rs_load<64, 64, 2>(A, arow, H_, (c + 1) * 64, va);
      rs_load<128, 64, 4>(Bw, bcol, H_, (c + 1) * 64, vb);
    }
#pragma unroll
    for (int kh = 0; kh < 2; ++kh) {
      const int kkk = kh * 32 + ko;
      bf16x8 a[2], b[4];
#pragma unroll
      for (int i = 0; i < 2; ++i) a[i] = fragL<64>(As[cur], wm * 32 + i * 16 + r, kkk);
#pragma unroll
      for (int j = 0; j < 4; ++j) b[j] = fragL<64>(Bs[cur], wn * 64 + j * 16 + r, kkk);
#pragma unroll
      for (int i = 0; i < 2; ++i)
#pragma unroll
        for (int j = 0; j < 4; ++j)
          acc[i][j] = __builtin_amdgcn_mfma_f32_16x16x32_bf16(a[i], b[j], acc[i][j], 0, 0, 0);
    }
    if (c < 7) {
      rs_write<64, 64, 2>(As[cur ^ 1], va);
      rs_write<128, 64, 4>(Bs[cur ^ 1], vb);
    }
    __syncthreads();
    cur ^= 1;
  }
  const int r0 = (lane >> 4) * 4, c0 = lane & 15;
#pragma unroll
  for (int i = 0; i < 2; ++i)
#pragma unroll
    for (int j = 0; j < 4; ++j) {
      int col = bcol + wn * 64 + j * 16 + c0;
      float bv = bias[col];
#pragma unroll
      for (int rr = 0; rr < 4; ++rr)
        C[(size_t)(arow + wm * 32 + i * 16 + r0 + rr) * H3 + col] = f2b(acc[i][j][rr] + bv);
    }
}

struct SArgs {
  const short* zgx; const short* egx; const int* target;
  float* h0f0; float* h0f1; short* h0b0; short* h0b1;
  float* h1f; short* h1b;
  short* gh0; short* gh1; short* gx1;
  const short* Wb_hh0; const float* b_hh0;
  const short* Wb_ih1; const float* b_ih1;
  const short* Wb_hh1; const float* b_hh1;
  const short* Wb_out; const float* fc_out_b;
  float* out;
};

DI void unit_pw1(const SArgs& a, int v, int t, char* smem) {
  short* sh = (short*)smem;
  const int row0 = v * 16;
  const int tid = threadIdx.x;
  const int tlog = t - 1;
#pragma unroll 1
  for (int c = 0; c < 4; ++c) {
    int f = c * 2048 + tid * 8;
    int rl = f >> 9, j = f & 511;
    int row = row0 + rl;
    const short* gx = a.gx1 + (size_t)row * H3 + j;
    const short* gh = a.gh1 + (size_t)row * H3 + j;
    float* hf = a.h1f + (size_t)row * H_ + j;
    bf16x8 xr = *(const bf16x8*)(gx);
    bf16x8 xz = *(const bf16x8*)(gx + H_);
    bf16x8 xn = *(const bf16x8*)(gx + 2 * H_);
    bf16x8 hr = *(const bf16x8*)(gh);
    bf16x8 hz = *(const bf16x8*)(gh + H_);
    bf16x8 hn = *(const bf16x8*)(gh + 2 * H_);
    float4 hp0 = *(const float4*)(hf);
    float4 hp1 = *(const float4*)(hf + 4);
    float hp[8] = {hp0.x, hp0.y, hp0.z, hp0.w, hp1.x, hp1.y, hp1.z, hp1.w};
    float hv[8];
    bf16x8 ov;
#pragma unroll
    for (int e = 0; e < 8; ++e) {
      hv[e] = gru_one(b2f(xr[e]), b2f(xz[e]), b2f(xn[e]),
                      b2f(hr[e]), b2f(hz[e]), b2f(hn[e]), hp[e]);
      ov[e] = f2b(hv[e]);
    }
    *(float4*)(hf) = make_float4(hv[0], hv[1], hv[2], hv[3]);
    *(float4*)(hf + 4) = make_float4(hv[4], hv[5], hv[6], hv[7]);
    *(bf16x8*)(a.h1b + (size_t)row * H_ + j) = ov;
    *(bf16x8*)(&sh[rl * 520 + j]) = ov;
  }
  __syncthreads();
  const int lane = tid & 63, w = tid >> 6;
  const int c0 = lane & 15, ko = (lane >> 4) * 8;
  f32x4 acc = {};
  const short* wb = a.Wb_out + (size_t)(w * 16 + c0) * H_ + ko;
  const short* ap = &sh[c0 * 520 + ko];
#pragma unroll
  for (int m = 0; m < 16; ++m) {
    bf16x8 av = *(const bf16x8*)(ap + m * 32);
    bf16x8 bw = *(const bf16x8*)(wb + m * 32);
    acc = __builtin_amdgcn_mfma_f32_16x16x32_bf16(av, bw, acc, 0, 0, 0);
  }
  const int r0 = (lane >> 4) * 4;
  const int col = w * 16 + c0;
  const float bv = a.fc_out_b[col];
#pragma unroll
  for (int rr = 0; rr < 4; ++rr) {
    int brow = row0 + r0 + rr;
    a.out[((size_t)brow * T_ + tlog) * V_ + col] = acc[rr] + bv;
  }
}

DI void unit_pw0gx1(const SArgs& a, int v, int t, char* smem) {
  const int p = t & 1;
  const float* h0f_prev = p ? a.h0f1 : a.h0f0;
  float* h0f_new = p ? a.h0f0 : a.h0f1;
  short* h0b_new = p ? a.h0b0 : a.h0b1;
  const int mt = v / 6, nt = v % 6;
  const int mbase = mt * 32, nb = nt * 256;
  const int tid = threadIdx.x;
  char* hns = smem;
  char* Bs = smem + 32768;
  bf16x8 vb[4];
  rs_load<256, 32, 4>(a.Wb_ih1, nb, H_, 0, vb);
#pragma unroll 1
  for (int c = 0; c < 8; ++c) {
    int f = c * 2048 + tid * 8;
    int rl = f >> 9, j = f & 511;
    int row = mbase + rl;
    int tok = (t == 0) ? 1 : a.target[(size_t)row * T_ + (t - 1)];
    const short* zg = a.zgx + (size_t)row * H3 + j;
    const short* eg = a.egx + (size_t)tok * H3 + j;
    const short* gh = a.gh0 + (size_t)row * H3 + j;
    const float* hf = h0f_prev + (size_t)row * H_ + j;
    bf16x8 zr = *(const bf16x8*)(zg);
    bf16x8 zz = *(const bf16x8*)(zg + H_);
    bf16x8 zn = *(const bf16x8*)(zg + 2 * H_);
    bf16x8 er = *(const bf16x8*)(eg);
    bf16x8 ez = *(const bf16x8*)(eg + H_);
    bf16x8 en = *(const bf16x8*)(eg + 2 * H_);
    bf16x8 hr = *(const bf16x8*)(gh);
    bf16x8 hz = *(const bf16x8*)(gh + H_);
    bf16x8 hn = *(const bf16x8*)(gh + 2 * H_);
    float4 hp0 = *(const float4*)(hf);
    float4 hp1 = *(const float4*)(hf + 4);
    float hp[8] = {hp0.x, hp0.y, hp0.z, hp0.w, hp1.x, hp1.y, hp1.z, hp1.w};
    float hv[8];
    bf16x8 ov;
#pragma unroll
    for (int e = 0; e < 8; ++e) {
      hv[e] = gru_one(b2f(zr[e]) + b2f(er[e]), b2f(zz[e]) + b2f(ez[e]),
                      b2f(zn[e]) + b2f(en[e]),
                      b2f(hr[e]), b2f(hz[e]), b2f(hn[e]), hp[e]);
      ov[e] = f2b(hv[e]);
    }
    *(bf16x8*)(hns + (rl << 10) + ((j << 1) ^ ((rl & 7) << 4))) = ov;
    if (nt == 0) {
      float* ho = h0f_new + (size_t)row * H_ + j;
      *(float4*)(ho) = make_float4(hv[0], hv[1], hv[2], hv[3]);
      *(float4*)(ho + 4) = make_float4(hv[4], hv[5], hv[6], hv[7]);
      *(bf16x8*)(h0b_new + (size_t)row * H_ + j) = ov;
    }
  }
  __syncthreads();
  rs_write<256, 32, 4>(Bs, vb);
  __syncthreads();
  const int lane = tid & 63, wid = tid >> 6;
  const int r = lane & 15, ko = (lane >> 4) * 8;
  f32x4 acc[2][4] = {};
  for (int c = 0; c < 16; ++c) {
    if (c < 15) rs_load<256, 32, 4>(a.Wb_ih1, nb, H_, (c + 1) * 32, vb);
    bf16x8 av[2], bv2[4];
#pragma unroll
    for (int i = 0; i < 2; ++i) {
      int row = i * 16 + r;
      av[i] = *(const bf16x8*)(hns + (row << 10) + ((((c * 32 + ko) << 1)) ^ ((row & 7) << 4)));
    }
#pragma unroll
    for (int j = 0; j < 4; ++j) bv2[j] = fragL<32>(Bs, wid * 64 + j * 16 + r, ko);
#pragma unroll
    for (int i = 0; i < 2; ++i)
#pragma unroll
      for (int j = 0; j < 4; ++j)
        acc[i][j] = __builtin_amdgcn_mfma_f32_16x16x32_bf16(av[i], bv2[j], acc[i][j], 0, 0, 0);
    __syncthreads();
    if (c < 15) {
      rs_write<256, 32, 4>(Bs, vb);
      __syncthreads();
    }
  }
  const int r0 = (lane >> 4) * 4, c0 = lane & 15;
#pragma unroll
  for (int i = 0; i < 2; ++i)
#pragma unroll
    for (int j = 0; j < 4; ++j) {
      int col = nb + wid * 64 + j * 16 + c0;
      float bvv = a.b_ih1[col];
#pragma unroll
      for (int rr = 0; rr < 4; ++rr)
        a.gx1[(size_t)(mbase + i * 16 + r0 + rr) * H3 + col] = f2b(acc[i][j][rr] + bvv);
    }
}

DI void phaseA(const SArgs& a, int t, char* smem, int bid, int nbk) {
  const short* h0b_cur = (t & 1) ? a.h0b1 : a.h0b0;
  for (int u = bid; u < 512; u += nbk) {
    if (u < 384) {
      if (t < T_)
        gemm_64x128_db(h0b_cur, a.Wb_hh0, a.b_hh0, a.gh0, (u / 12) * 64, (u % 12) * 128, smem);
    } else if (t >= 1) {
      unit_pw1(a, u - 384, t, smem);
    }
    __syncthreads();
  }
}
DI void phaseB(const SArgs& a, int t, char* smem, int bid, int nbk) {
  for (int u = bid; u < 768; u += nbk) {
    if (u < 384)
      gemm_64x128_db(a.h1b, a.Wb_hh1, a.b_hh1, a.gh1, (u / 12) * 64, (u % 12) * 128, smem);
    else
      unit_pw0gx1(a, u - 384, t, smem);
    __syncthreads();
  }
}
__global__ __launch_bounds__(256) void k_phA(SArgs a, int t) {
  extern __shared__ char smem[];
  phaseA(a, t, smem, blockIdx.x, gridDim.x);
}
__global__ __launch_bounds__(256) void k_phB(SArgs a, int t) {
  extern __shared__ char smem[];
  phaseB(a, t, smem, blockIdx.x, gridDim.x);
}

// ================= prep kernels =================
template <int MI, int NJ>
DI void gemm_wave_global(const short* __restrict__ A, const short* __restrict__ B,
                         const int K, const int arow, const int bcol,
                         f32x4 (&acc)[MI][NJ]) {
  const int lane = threadIdx.x & 63;
  const int r = lane & 15, ko = (lane >> 4) * 8;
  const short* Ap = A + (size_t)(arow + r) * K + ko;
  const short* Bp = B + (size_t)(bcol + r) * K + ko;
  for (int kk = 0; kk < K; kk += 32) {
    bf16x8 a[MI], b[NJ];
#pragma unroll
    for (int i = 0; i < MI; ++i) a[i] = *(const bf16x8*)(Ap + (size_t)i * 16 * K + kk);
#pragma unroll
    for (int j = 0; j < NJ; ++j) b[j] = *(const bf16x8*)(Bp + (size_t)j * 16 * K + kk);
#pragma unroll
    for (int i = 0; i < MI; ++i)
#pragma unroll
      for (int j = 0; j < NJ; ++j)
        acc[i][j] = __builtin_amdgcn_mfma_f32_16x16x32_bf16(a[i], b[j], acc[i][j], 0, 0, 0);
  }
}
template <int MI, int NJ>
DI void epi_store_bf16(short* __restrict__ C, const float* __restrict__ bias,
                       const int N, const int arow, const int bcol, f32x4 (&acc)[MI][NJ]) {
  const int lane = threadIdx.x & 63;
  const int r0 = (lane >> 4) * 4, c0 = lane & 15;
#pragma unroll
  for (int i = 0; i < MI; ++i)
#pragma unroll
    for (int j = 0; j < NJ; ++j) {
      int col = bcol + j * 16 + c0;
      float bv = bias[col];
#pragma unroll
      for (int rr = 0; rr < 4; ++rr)
        C[(size_t)(arow + i * 16 + r0 + rr) * N + col] = f2b(acc[i][j][rr] + bv);
    }
}

__global__ __launch_bounds__(256) void k_prep0(
    const float* __restrict__ W_hh0, const float* __restrict__ W_ih1,
    const float* __restrict__ W_hh1, const float* __restrict__ fc_out_w,
    const float* __restrict__ W_ih0, const float* __restrict__ fc_hidden_w,
    const float* __restrict__ z,
    short* Wb_hh0, short* Wb_ih1, short* Wb_hh1, short* Wb_out,
    short* Wb_ih0z, short* Wb_fch, short* z_b) {
  const int n1 = H3 * H_;
  const int n2 = V_ * H_;
  const int n3 = H3 * LAT_;
  const int n4 = (2 * H_) * LAT_;
  const int n5 = B_ * LAT_;
  const int total = n1 * 3 + n2 + n3 + n4 + n5;
  for (int i = blockIdx.x * blockDim.x + threadIdx.x; i < total;
       i += gridDim.x * blockDim.x) {
    int idx = i;
    if (idx < n1) { Wb_hh0[idx] = f2b(W_hh0[idx]); continue; }
    idx -= n1;
    if (idx < n1) { Wb_ih1[idx] = f2b(W_ih1[idx]); continue; }
    idx -= n1;
    if (idx < n1) { Wb_hh1[idx] = f2b(W_hh1[idx]); continue; }
    idx -= n1;
    if (idx < n2) { Wb_out[idx] = f2b(fc_out_w[idx]); continue; }
    idx -= n2;
    if (idx < n3) {
      int n = idx >> 8, k = idx & 255;
      Wb_ih0z[idx] = f2b(W_ih0[(size_t)n * (E_ + LAT_) + E_ + k]);
      continue;
    }
    idx -= n3;
    if (idx < n4) { Wb_fch[idx] = f2b(fc_hidden_w[idx]); continue; }
    idx -= n4;
    z_b[idx] = f2b(z[idx]);
  }
}

__global__ __launch_bounds__(256) void k_prep_emb(const float* __restrict__ embed,
                                                  const float* __restrict__ W_ih0,
                                                  short* __restrict__ egx) {
  __shared__ float er[E_];
  int v = blockIdx.x;
  for (int e = threadIdx.x; e < E_; e += blockDim.x) er[e] = embed[(size_t)v * E_ + e];
  __syncthreads();
  for (int n = threadIdx.x; n < H3; n += blockDim.x) {
    const float* w = W_ih0 + (size_t)n * (E_ + LAT_);
    float acc = 0.f;
#pragma unroll 8
    for (int e = 0; e < E_; ++e) acc += er[e] * w[e];
    egx[(size_t)v * H3 + n] = f2b(acc);
  }
}

__global__ __launch_bounds__(256) void k_prep1(
    const short* __restrict__ z_b, const short* __restrict__ Wb_ih0z,
    const short* __restrict__ Wb_fch, const float* __restrict__ b_ih0,
    const float* __restrict__ fc_hidden_b,
    short* zgx, float* h0f, float* h1f, short* h0b, short* h1b) {
  const int bid = blockIdx.x;
  const int mtile = bid / 20, ntile = bid % 20;
  const int tid = threadIdx.x, lane = tid & 63, wid = tid >> 6;
  const int wm = wid >> 1, wn = wid & 1;
  const int arow = mtile * 128 + wm * 64;
  f32x4 acc[4][4] = {};
  if (ntile < 12) {
    int bcol = ntile * 128 + wn * 64;
    gemm_wave_global<4, 4>(z_b, Wb_ih0z, LAT_, arow, bcol, acc);
    epi_store_bf16<4, 4>(zgx, b_ih0, H3, arow, bcol, acc);
  } else {
    int bcol = (ntile - 12) * 128 + wn * 64;
    gemm_wave_global<4, 4>(z_b, Wb_fch, LAT_, arow, bcol, acc);
    const int r0 = (lane >> 4) * 4, c0 = lane & 15;
#pragma unroll
    for (int i = 0; i < 4; ++i)
#pragma unroll
      for (int j = 0; j < 4; ++j) {
        int col = bcol + j * 16 + c0;
        float bv = fc_hidden_b[col];
#pragma unroll
        for (int rr = 0; rr < 4; ++rr) {
          int row = arow + i * 16 + r0 + rr;
          float v = acc[i][j][rr] + bv;
          if (col < H_) {
            h0f[(size_t)row * H_ + col] = v;
            h0b[(size_t)row * H_ + col] = f2b(v);
          } else {
            h1f[(size_t)row * H_ + (col - H_)] = v;
            h1b[(size_t)row * H_ + (col - H_)] = f2b(v);
          }
        }
      }
  }
}

extern "C" void kernel_launch(void* const* d_in, const int* in_sizes, int n_in,
                              void* d_out, int out_size, void* d_ws, size_t ws_size,
                              hipStream_t stream) {
  const float* z           = (const float*)d_in[0];
  const int*   target      = (const int*)d_in[1];
  const float* embed       = (const float*)d_in[2];
  const float* fc_hidden_w = (const float*)d_in[3];
  const float* fc_hidden_b = (const float*)d_in[4];
  const float* W_ih0       = (const float*)d_in[5];
  const float* W_hh0       = (const float*)d_in[6];
  const float* b_ih0       = (const float*)d_in[7];
  const float* b_hh0       = (const float*)d_in[8];
  const float* W_ih1       = (const float*)d_in[9];
  const float* W_hh1       = (const float*)d_in[10];
  const float* b_ih1       = (const float*)d_in[11];
  const float* b_hh1       = (const float*)d_in[12];
  const float* fc_out_w    = (const float*)d_in[13];
  const float* fc_out_b    = (const float*)d_in[14];
  float* out = (float*)d_out;

  char* ws = (char*)d_ws;
  size_t off = 0;
  auto alloc = [&](size_t bytes) -> void* {
    off = (off + 255) & ~(size_t)255;
    void* p = ws + off;
    off += bytes;
    return p;
  };
  float* h0f0   = (float*)alloc((size_t)B_ * H_ * 4);
  float* h0f1   = (float*)alloc((size_t)B_ * H_ * 4);
  float* h1f    = (float*)alloc((size_t)B_ * H_ * 4);
  short* h0b0   = (short*)alloc((size_t)B_ * H_ * 2);
  short* h0b1   = (short*)alloc((size_t)B_ * H_ * 2);
  short* h1b    = (short*)alloc((size_t)B_ * H_ * 2);
  short* gh0    = (short*)alloc((size_t)B_ * H3 * 2);
  short* gh1    = (short*)alloc((size_t)B_ * H3 * 2);
  short* gx1    = (short*)alloc((size_t)B_ * H3 * 2);
  short* zgx    = (short*)alloc((size_t)B_ * H3 * 2);
  short* egx    = (short*)alloc((size_t)V_ * H3 * 2);
  short* Wb_hh0 = (short*)alloc((size_t)H3 * H_ * 2);
  short* Wb_ih1 = (short*)alloc((size_t)H3 * H_ * 2);
  short* Wb_hh1 = (short*)alloc((size_t)H3 * H_ * 2);
  short* Wb_out = (short*)alloc((size_t)V_ * H_ * 2);
  short* Wb_ih0z= (short*)alloc((size_t)H3 * LAT_ * 2);
  short* Wb_fch = (short*)alloc((size_t)2 * H_ * LAT_ * 2);
  short* z_b    = (short*)alloc((size_t)B_ * LAT_ * 2);
  if (off > ws_size) return;

  k_prep0<<<2048, 256, 0, stream>>>(W_hh0, W_ih1, W_hh1, fc_out_w, W_ih0, fc_hidden_w,
                                    z, Wb_hh0, Wb_ih1, Wb_hh1, Wb_out, Wb_ih0z, Wb_fch, z_b);
  k_prep_emb<<<64, 256, 0, stream>>>(embed, W_ih0, egx);
  k_prep1<<<320, 256, 0, stream>>>(z_b, Wb_ih0z, Wb_fch, b_ih0, fc_hidden_b,
                                   zgx, h0f0, h1f, h0b0, h1b);

  RArgs r;
  r.zgx = zgx; r.egx = egx; r.target = target;
  r.h0f = h0f0; r.h1f = h1f; r.h0b = h0b0; r.h1b = h1b;
  r.Wb_hh0 = Wb_hh0; r.b_hh0 = b_hh0;
  r.Wb_ih1 = Wb_ih1; r.b_ih1 = b_ih1;
  r.Wb_hh1 = Wb_hh1; r.b_hh1 = b_hh1;
  r.Wb_out = Wb_out; r.fc_out_b = fc_out_b;
  r.out = out;

  hipError_t ae = hipFuncSetAttribute(
      reinterpret_cast<const void*>(k_row),
      hipFuncAttributeMaxDynamicSharedMemorySize, 163840);
  bool ok = (ae == hipSuccess);
  if (ok) {
    k_row<<<64, 256, 163840, stream>>>(r);
    if (hipPeekAtLastError() != hipSuccess) {
      (void)hipGetLastError();
      ok = false;
    }
  }
  if (!ok) {
    // fallback: proven multi-launch schedule (math-identical to R3/R4)
    SArgs a;
    a.zgx = zgx; a.egx = egx; a.target = target;
    a.h0f0 = h0f0; a.h0f1 = h0f1; a.h0b0 = h0b0; a.h0b1 = h0b1;
    a.h1f = h1f; a.h1b = h1b;
    a.gh0 = gh0; a.gh1 = gh1; a.gx1 = gx1;
    a.Wb_hh0 = Wb_hh0; a.b_hh0 = b_hh0;
    a.Wb_ih1 = Wb_ih1; a.b_ih1 = b_ih1;
    a.Wb_hh1 = Wb_hh1; a.b_hh1 = b_hh1;
    a.Wb_out = Wb_out; a.fc_out_b = fc_out_b;
    a.out = out;
    for (int t = 0; t < T_; ++t) {
      k_phA<<<512, 256, 49152, stream>>>(a, t);
      k_phB<<<768, 256, 49152, stream>>>(a, t);
    }
    k_phA<<<128, 256, 49152, stream>>>(a, T_);
  }
}

// Round 7
// 4389.243 us; speedup vs baseline: 6.7648x; 5.5855x over previous
//
#include <hip/hip_runtime.h>
#include <hip/hip_bf16.h>

#define DI __device__ __forceinline__

typedef short bf16x8 __attribute__((ext_vector_type(8)));
typedef float f32x4 __attribute__((ext_vector_type(4)));

constexpr int B_ = 2048, T_ = 120, V_ = 64, E_ = 128, H_ = 512, LAT_ = 256;
constexpr int H3 = 1536;  // 3*H

DI short f2b(float f) {
  union { __hip_bfloat16 h; short s; } u;
  u.h = __float2bfloat16(f);
  return u.s;
}
DI float b2f(short s) {
  union { unsigned u; float f; } x;
  x.u = (unsigned)(unsigned short)s << 16;
  return x.f;
}
DI float sigm(float x) { return 1.f / (1.f + __expf(-x)); }
DI float tanh_f(float x) {
  x = fminf(15.f, fmaxf(-15.f, x));
  float e = __expf(2.f * x);
  return (e - 1.f) / (e + 1.f);
}
DI float gru_one(float xr, float xz, float xn, float hr, float hz, float hn, float hp) {
  float r = sigm(xr + hr);
  float u = sigm(xz + hz);
  float nn = tanh_f(xn + r * hn);
  return (1.f - u) * nn + u * hp;
}
// pre-summed form: sr = xr+hr, sz = xz+hz; xn, hn separate
DI float gru_pre(float sr, float sz, float xn, float hn, float hp) {
  float r = sigm(sr);
  float u = sigm(sz);
  float nn = tanh_f(xn + r * hn);
  return (1.f - u) * nn + u * hp;
}

// ======== register staging: global -> regs -> swizzled ds_write (256 threads) ========
template <int ROWS, int BK, int NV>
DI void rs_load(const short* __restrict__ G, int row0, int K, int kk, bf16x8 (&v)[NV]) {
  constexpr int SLOTS = BK / 8;
  constexpr int RPP = 2048 / BK;
  static_assert(NV == ROWS / RPP, "NV mismatch");
  const int tid = threadIdx.x;
  const int rl = tid / SLOTS, sl = tid % SLOTS;
#pragma unroll
  for (int p = 0; p < NV; ++p)
    v[p] = *(const bf16x8*)(G + (size_t)(row0 + p * RPP + rl) * K + kk + sl * 8);
}
template <int ROWS, int BK, int NV>
DI void rs_write(char* __restrict__ lds, bf16x8 (&v)[NV]) {
  constexpr int SLOTS = BK / 8;
  constexpr int RPP = 2048 / BK;
  const int tid = threadIdx.x;
  const int rl = tid / SLOTS, sl = tid % SLOTS;
#pragma unroll
  for (int p = 0; p < NV; ++p) {
    int row = p * RPP + rl;
    *(bf16x8*)(lds + row * (SLOTS * 16) + ((sl ^ (row & (SLOTS - 1))) * 16)) = v[p];
  }
}
template <int BK>
DI bf16x8 fragL(const char* __restrict__ lds, int row, int kk) {
  return *(const bf16x8*)(lds + row * (BK * 2) + ((kk << 1) ^ ((row & (BK / 8 - 1)) << 4)));
}

// ======== core 64x128 GEMM: acc = A[64x512] @ W[128x512]^T, dbuf LDS (48KB) ========
DI void gemm_core(const short* __restrict__ A, const short* __restrict__ Bw,
                  int arow, int bcol, char* lds, f32x4 (&acc)[2][4]) {
  char* As[2] = {lds, lds + 8192};
  char* Bs[2] = {lds + 16384, lds + 32768};
  const int tid = threadIdx.x, lane = tid & 63, wid = tid >> 6;
  const int wm = wid >> 1, wn = wid & 1;
  const int r = lane & 15, ko = (lane >> 4) * 8;
  bf16x8 va[2], vb[4];
  rs_load<64, 64, 2>(A, arow, H_, 0, va);
  rs_load<128, 64, 4>(Bw, bcol, H_, 0, vb);
  rs_write<64, 64, 2>(As[0], va);
  rs_write<128, 64, 4>(Bs[0], vb);
  __syncthreads();
  int cur = 0;
  for (int c = 0; c < 8; ++c) {
    if (c < 7) {
      rs_load<64, 64, 2>(A, arow, H_, (c + 1) * 64, va);
      rs_load<128, 64, 4>(Bw, bcol, H_, (c + 1) * 64, vb);
    }
#pragma unroll
    for (int kh = 0; kh < 2; ++kh) {
      const int kkk = kh * 32 + ko;
      bf16x8 a[2], b[4];
#pragma unroll
      for (int i = 0; i < 2; ++i) a[i] = fragL<64>(As[cur], wm * 32 + i * 16 + r, kkk);
#pragma unroll
      for (int j = 0; j < 4; ++j) b[j] = fragL<64>(Bs[cur], wn * 64 + j * 16 + r, kkk);
#pragma unroll
      for (int i = 0; i < 2; ++i)
#pragma unroll
        for (int j = 0; j < 4; ++j)
          acc[i][j] = __builtin_amdgcn_mfma_f32_16x16x32_bf16(a[i], b[j], acc[i][j], 0, 0, 0);
    }
    if (c < 7) {
      rs_write<64, 64, 2>(As[cur ^ 1], va);
      rs_write<128, 64, 4>(Bs[cur ^ 1], vb);
    }
    __syncthreads();
    cur ^= 1;
  }
}

// ======== shared arg bundle ========
struct GArgs {
  const short* zgx; const short* egx; const int* target;
  float* h0f; float* h1f; short* h0b; short* h1b;
  short* p0;                    // [2048][4][512] bf16: sr, sz, xn, hn
  short* gx1a; short* gx1b;     // ping-pong [2048][1536]
  short* gh1;                   // [2048][1536]
  const short* Wb_hh0; const float* b_hh0;
  const short* Wb_ih1; const float* b_ih1;
  const short* Wb_hh1; const float* b_hh1;
  const short* Wb_out; const float* fc_out_b;
  float* out;
};

// ================= A(t): G0(t) -> p0 | X1(t-1) -> gx1 | P1(t-2)+logits =================
__global__ __launch_bounds__(256) void k_A(GArgs a, int t) {
  extern __shared__ char smem[];
  const int u = blockIdx.x;
  const int tid = threadIdx.x, lane = tid & 63, wid = tid >> 6;
  if (u < 384) {
    // ---- G0(t): gh0 GEMM, pack epilogue
    if (t >= T_) return;
    const int mt = u / 12, nt = u % 12;
    const int arow = mt * 64, bcol = nt * 128;
    f32x4 acc[2][4] = {};
    gemm_core(a.h0b, a.Wb_hh0, arow, bcol, smem, acc);
    const int wm = wid >> 1, wn = wid & 1;
    const int r0 = (lane >> 4) * 4, c0 = lane & 15;
    const int g = nt >> 2;  // whole 128-col tile lies in one gate
#pragma unroll
    for (int i = 0; i < 2; ++i)
#pragma unroll
      for (int j = 0; j < 4; ++j) {
        const int col = bcol + wn * 64 + j * 16 + c0;
        const int jj = col & 511;
        const float bv = a.b_hh0[col];
#pragma unroll
        for (int rr = 0; rr < 4; ++rr) {
          const int row = arow + wm * 32 + i * 16 + r0 + rr;
          const float val = acc[i][j][rr] + bv;  // h-side gate pre-act
          const int tok = (t == 0) ? 1 : a.target[(size_t)row * T_ + (t - 1)];
          const float xv = b2f(a.zgx[(size_t)row * H3 + g * 512 + jj]) +
                           b2f(a.egx[(size_t)tok * H3 + g * 512 + jj]);
          short* pr = a.p0 + ((size_t)row * 4) * 512 + jj;
          if (g < 2) {
            pr[g * 512] = f2b(val + xv);        // sr or sz
          } else {
            pr[2 * 512] = f2b(xv);              // xn
            pr[3 * 512] = f2b(val);             // hn
          }
        }
      }
    return;
  }
  if (u < 768) {
    // ---- X1(t-1): gx1 GEMM (plain epilogue + b_ih1)
    if (t < 1 || t > T_) return;
    short* gxw = ((t - 1) & 1) ? a.gx1b : a.gx1a;
    const int uu = u - 384;
    const int mt = uu / 12, nt = uu % 12;
    const int arow = mt * 64, bcol = nt * 128;
    f32x4 acc[2][4] = {};
    gemm_core(a.h0b, a.Wb_ih1, arow, bcol, smem, acc);
    const int wm = wid >> 1, wn = wid & 1;
    const int r0 = (lane >> 4) * 4, c0 = lane & 15;
#pragma unroll
    for (int i = 0; i < 2; ++i)
#pragma unroll
      for (int j = 0; j < 4; ++j) {
        const int col = bcol + wn * 64 + j * 16 + c0;
        const float bv = a.b_ih1[col];
#pragma unroll
        for (int rr = 0; rr < 4; ++rr)
          gxw[(size_t)(arow + wm * 32 + i * 16 + r0 + rr) * H3 + col] = f2b(acc[i][j][rr] + bv);
      }
    return;
  }
  // ---- P1(t-2) + logits(t-2): 16-row band
  if (t < 2) return;
  const short* gxr = (t & 1) ? a.gx1b : a.gx1a;  // (t-2)&1 == t&1
  short* sh = (short*)smem;
  const int row0 = (u - 768) * 16;
  const int tlog = t - 2;
#pragma unroll 1
  for (int c = 0; c < 4; ++c) {
    int f = c * 2048 + tid * 8;
    int rl = f >> 9, j = f & 511;
    int row = row0 + rl;
    const short* gx = gxr + (size_t)row * H3 + j;
    const short* gh = a.gh1 + (size_t)row * H3 + j;
    float* hf = a.h1f + (size_t)row * H_ + j;
    bf16x8 xr = *(const bf16x8*)(gx);
    bf16x8 xz = *(const bf16x8*)(gx + H_);
    bf16x8 xn = *(const bf16x8*)(gx + 2 * H_);
    bf16x8 hr = *(const bf16x8*)(gh);
    bf16x8 hz = *(const bf16x8*)(gh + H_);
    bf16x8 hn = *(const bf16x8*)(gh + 2 * H_);
    float4 hp0 = *(const float4*)(hf);
    float4 hp1 = *(const float4*)(hf + 4);
    float hp[8] = {hp0.x, hp0.y, hp0.z, hp0.w, hp1.x, hp1.y, hp1.z, hp1.w};
    float hv[8];
    bf16x8 ov;
#pragma unroll
    for (int e = 0; e < 8; ++e) {
      hv[e] = gru_one(b2f(xr[e]), b2f(xz[e]), b2f(xn[e]),
                      b2f(hr[e]), b2f(hz[e]), b2f(hn[e]), hp[e]);
      ov[e] = f2b(hv[e]);
    }
    *(float4*)(hf) = make_float4(hv[0], hv[1], hv[2], hv[3]);
    *(float4*)(hf + 4) = make_float4(hv[4], hv[5], hv[6], hv[7]);
    *(bf16x8*)(a.h1b + (size_t)row * H_ + j) = ov;
    *(bf16x8*)(&sh[rl * 520 + j]) = ov;
  }
  __syncthreads();
  const int w = tid >> 6;
  const int c0 = lane & 15, ko = (lane >> 4) * 8;
  f32x4 acc = {};
  const short* wb = a.Wb_out + (size_t)(w * 16 + c0) * H_ + ko;
  const short* ap = &sh[c0 * 520 + ko];
#pragma unroll
  for (int m = 0; m < 16; ++m) {
    bf16x8 av = *(const bf16x8*)(ap + m * 32);
    bf16x8 bw = *(const bf16x8*)(wb + m * 32);
    acc = __builtin_amdgcn_mfma_f32_16x16x32_bf16(av, bw, acc, 0, 0, 0);
  }
  const int r0 = (lane >> 4) * 4;
  const int col = w * 16 + c0;
  const float bv = a.fc_out_b[col];
#pragma unroll
  for (int rr = 0; rr < 4; ++rr) {
    int brow = row0 + r0 + rr;
    a.out[((size_t)brow * T_ + tlog) * V_ + col] = acc[rr] + bv;
  }
}

// ================= C(t): Dp(t) pw0 | G1(t-1) gh1 GEMM =================
__global__ __launch_bounds__(256) void k_C(GArgs a, int t) {
  extern __shared__ char smem[];
  const int u = blockIdx.x;
  const int tid = threadIdx.x;
  if (u < 128) {
    // ---- Dp(t): pw0 elementwise on 16-row band (reads p0, updates h0f/h0b)
    if (t >= T_) return;
    const int row0 = u * 16;
#pragma unroll 1
    for (int it = 0; it < 4; ++it) {
      int v = it * 256 + tid;       // 1024 vec8-units per block
      int rl = v >> 6, jb = v & 63;
      int row = row0 + rl, j = jb * 8;
      const short* pr = a.p0 + ((size_t)row * 4) * 512 + j;
      bf16x8 sr = *(const bf16x8*)(pr);
      bf16x8 sz = *(const bf16x8*)(pr + 512);
      bf16x8 xn = *(const bf16x8*)(pr + 1024);
      bf16x8 hn = *(const bf16x8*)(pr + 1536);
      float* hf = a.h0f + (size_t)row * H_ + j;
      float4 hp0 = *(const float4*)(hf);
      float4 hp1 = *(const float4*)(hf + 4);
      float hp[8] = {hp0.x, hp0.y, hp0.z, hp0.w, hp1.x, hp1.y, hp1.z, hp1.w};
      float hv[8];
      bf16x8 ov;
#pragma unroll
      for (int e = 0; e < 8; ++e) {
        hv[e] = gru_pre(b2f(sr[e]), b2f(sz[e]), b2f(xn[e]), b2f(hn[e]), hp[e]);
        ov[e] = f2b(hv[e]);
      }
      *(float4*)(hf) = make_float4(hv[0], hv[1], hv[2], hv[3]);
      *(float4*)(hf + 4) = make_float4(hv[4], hv[5], hv[6], hv[7]);
      *(bf16x8*)(a.h0b + (size_t)row * H_ + j) = ov;
    }
    return;
  }
  // ---- G1(t-1): gh1 GEMM (plain epilogue + b_hh1)
  if (t < 1 || t > T_) return;
  const int uu = u - 128;
  const int mt = uu / 12, nt = uu % 12;
  const int arow = mt * 64, bcol = nt * 128;
  f32x4 acc[2][4] = {};
  gemm_core(a.h1b, a.Wb_hh1, arow, bcol, smem, acc);
  const int lane = tid & 63, wid = tid >> 6;
  const int wm = wid >> 1, wn = wid & 1;
  const int r0 = (lane >> 4) * 4, c0 = lane & 15;
#pragma unroll
  for (int i = 0; i < 2; ++i)
#pragma unroll
    for (int j = 0; j < 4; ++j) {
      const int col = bcol + wn * 64 + j * 16 + c0;
      const float bv = a.b_hh1[col];
#pragma unroll
      for (int rr = 0; rr < 4; ++rr)
        a.gh1[(size_t)(arow + wm * 32 + i * 16 + r0 + rr) * H3 + col] = f2b(acc[i][j][rr] + bv);
    }
}

// ================= prep kernels =================
template <int MI, int NJ>
DI void gemm_wave_global(const short* __restrict__ A, const short* __restrict__ B,
                         const int K, const int arow, const int bcol,
                         f32x4 (&acc)[MI][NJ]) {
  const int lane = threadIdx.x & 63;
  const int r = lane & 15, ko = (lane >> 4) * 8;
  const short* Ap = A + (size_t)(arow + r) * K + ko;
  const short* Bp = B + (size_t)(bcol + r) * K + ko;
  for (int kk = 0; kk < K; kk += 32) {
    bf16x8 a[MI], b[NJ];
#pragma unroll
    for (int i = 0; i < MI; ++i) a[i] = *(const bf16x8*)(Ap + (size_t)i * 16 * K + kk);
#pragma unroll
    for (int j = 0; j < NJ; ++j) b[j] = *(const bf16x8*)(Bp + (size_t)j * 16 * K + kk);
#pragma unroll
    for (int i = 0; i < MI; ++i)
#pragma unroll
      for (int j = 0; j < NJ; ++j)
        acc[i][j] = __builtin_amdgcn_mfma_f32_16x16x32_bf16(a[i], b[j], acc[i][j], 0, 0, 0);
  }
}
template <int MI, int NJ>
DI void epi_store_bf16(short* __restrict__ C, const float* __restrict__ bias,
                       const int N, const int arow, const int bcol, f32x4 (&acc)[MI][NJ]) {
  const int lane = threadIdx.x & 63;
  const int r0 = (lane >> 4) * 4, c0 = lane & 15;
#pragma unroll
  for (int i = 0; i < MI; ++i)
#pragma unroll
    for (int j = 0; j < NJ; ++j) {
      int col = bcol + j * 16 + c0;
      float bv = bias[col];
#pragma unroll
      for (int rr = 0; rr < 4; ++rr)
        C[(size_t)(arow + i * 16 + r0 + rr) * N + col] = f2b(acc[i][j][rr] + bv);
    }
}

__global__ __launch_bounds__(256) void k_prep0(
    const float* __restrict__ W_hh0, const float* __restrict__ W_ih1,
    const float* __restrict__ W_hh1, const float* __restrict__ fc_out_w,
    const float* __restrict__ W_ih0, const float* __restrict__ fc_hidden_w,
    const float* __restrict__ z,
    short* Wb_hh0, short* Wb_ih1, short* Wb_hh1, short* Wb_out,
    short* Wb_ih0z, short* Wb_fch, short* z_b) {
  const int n1 = H3 * H_;
  const int n2 = V_ * H_;
  const int n3 = H3 * LAT_;
  const int n4 = (2 * H_) * LAT_;
  const int n5 = B_ * LAT_;
  const int total = n1 * 3 + n2 + n3 + n4 + n5;
  for (int i = blockIdx.x * blockDim.x + threadIdx.x; i < total;
       i += gridDim.x * blockDim.x) {
    int idx = i;
    if (idx < n1) { Wb_hh0[idx] = f2b(W_hh0[idx]); continue; }
    idx -= n1;
    if (idx < n1) { Wb_ih1[idx] = f2b(W_ih1[idx]); continue; }
    idx -= n1;
    if (idx < n1) { Wb_hh1[idx] = f2b(W_hh1[idx]); continue; }
    idx -= n1;
    if (idx < n2) { Wb_out[idx] = f2b(fc_out_w[idx]); continue; }
    idx -= n2;
    if (idx < n3) {
      int n = idx >> 8, k = idx & 255;
      Wb_ih0z[idx] = f2b(W_ih0[(size_t)n * (E_ + LAT_) + E_ + k]);
      continue;
    }
    idx -= n3;
    if (idx < n4) { Wb_fch[idx] = f2b(fc_hidden_w[idx]); continue; }
    idx -= n4;
    z_b[idx] = f2b(z[idx]);
  }
}

__global__ __launch_bounds__(256) void k_prep_emb(const float* __restrict__ embed,
                                                  const float* __restrict__ W_ih0,
                                                  short* __restrict__ egx) {
  __shared__ float er[E_];
  int v = blockIdx.x;
  for (int e = threadIdx.x; e < E_; e += blockDim.x) er[e] = embed[(size_t)v * E_ + e];
  __syncthreads();
  for (int n = threadIdx.x; n < H3; n += blockDim.x) {
    const float* w = W_ih0 + (size_t)n * (E_ + LAT_);
    float acc = 0.f;
#pragma unroll 8
    for (int e = 0; e < E_; ++e) acc += er[e] * w[e];
    egx[(size_t)v * H3 + n] = f2b(acc);
  }
}

__global__ __launch_bounds__(256) void k_prep1(
    const short* __restrict__ z_b, const short* __restrict__ Wb_ih0z,
    const short* __restrict__ Wb_fch, const float* __restrict__ b_ih0,
    const float* __restrict__ fc_hidden_b,
    short* zgx, float* h0f, float* h1f, short* h0b, short* h1b) {
  const int bid = blockIdx.x;
  const int mtile = bid / 20, ntile = bid % 20;
  const int tid = threadIdx.x, lane = tid & 63, wid = tid >> 6;
  const int wm = wid >> 1, wn = wid & 1;
  const int arow = mtile * 128 + wm * 64;
  f32x4 acc[4][4] = {};
  if (ntile < 12) {
    int bcol = ntile * 128 + wn * 64;
    gemm_wave_global<4, 4>(z_b, Wb_ih0z, LAT_, arow, bcol, acc);
    epi_store_bf16<4, 4>(zgx, b_ih0, H3, arow, bcol, acc);
  } else {
    int bcol = (ntile - 12) * 128 + wn * 64;
    gemm_wave_global<4, 4>(z_b, Wb_fch, LAT_, arow, bcol, acc);
    const int r0 = (lane >> 4) * 4, c0 = lane & 15;
#pragma unroll
    for (int i = 0; i < 4; ++i)
#pragma unroll
      for (int j = 0; j < 4; ++j) {
        int col = bcol + j * 16 + c0;
        float bv = fc_hidden_b[col];
#pragma unroll
        for (int rr = 0; rr < 4; ++rr) {
          int row = arow + i * 16 + r0 + rr;
          float v = acc[i][j][rr] + bv;
          if (col < H_) {
            h0f[(size_t)row * H_ + col] = v;
            h0b[(size_t)row * H_ + col] = f2b(v);
          } else {
            h1f[(size_t)row * H_ + (col - H_)] = v;
            h1b[(size_t)row * H_ + (col - H_)] = f2b(v);
          }
        }
      }
  }
}

extern "C" void kernel_launch(void* const* d_in, const int* in_sizes, int n_in,
                              void* d_out, int out_size, void* d_ws, size_t ws_size,
                              hipStream_t stream) {
  const float* z           = (const float*)d_in[0];
  const int*   target      = (const int*)d_in[1];
  const float* embed       = (const float*)d_in[2];
  const float* fc_hidden_w = (const float*)d_in[3];
  const float* fc_hidden_b = (const float*)d_in[4];
  const float* W_ih0       = (const float*)d_in[5];
  const float* W_hh0       = (const float*)d_in[6];
  const float* b_ih0       = (const float*)d_in[7];
  const float* b_hh0       = (const float*)d_in[8];
  const float* W_ih1       = (const float*)d_in[9];
  const float* W_hh1       = (const float*)d_in[10];
  const float* b_ih1       = (const float*)d_in[11];
  const float* b_hh1       = (const float*)d_in[12];
  const float* fc_out_w    = (const float*)d_in[13];
  const float* fc_out_b    = (const float*)d_in[14];
  float* out = (float*)d_out;

  char* ws = (char*)d_ws;
  size_t off = 0;
  auto alloc = [&](size_t bytes) -> void* {
    off = (off + 255) & ~(size_t)255;
    void* p = ws + off;
    off += bytes;
    return p;
  };
  float* h0f    = (float*)alloc((size_t)B_ * H_ * 4);
  float* h1f    = (float*)alloc((size_t)B_ * H_ * 4);
  short* h0b    = (short*)alloc((size_t)B_ * H_ * 2);
  short* h1b    = (short*)alloc((size_t)B_ * H_ * 2);
  short* p0     = (short*)alloc((size_t)B_ * 4 * H_ * 2);
  short* gx1a   = (short*)alloc((size_t)B_ * H3 * 2);
  short* gx1b   = (short*)alloc((size_t)B_ * H3 * 2);
  short* gh1    = (short*)alloc((size_t)B_ * H3 * 2);
  short* zgx    = (short*)alloc((size_t)B_ * H3 * 2);
  short* egx    = (short*)alloc((size_t)V_ * H3 * 2);
  short* Wb_hh0 = (short*)alloc((size_t)H3 * H_ * 2);
  short* Wb_ih1 = (short*)alloc((size_t)H3 * H_ * 2);
  short* Wb_hh1 = (short*)alloc((size_t)H3 * H_ * 2);
  short* Wb_out = (short*)alloc((size_t)V_ * H_ * 2);
  short* Wb_ih0z= (short*)alloc((size_t)H3 * LAT_ * 2);
  short* Wb_fch = (short*)alloc((size_t)2 * H_ * LAT_ * 2);
  short* z_b    = (short*)alloc((size_t)B_ * LAT_ * 2);
  if (off > ws_size) return;

  k_prep0<<<2048, 256, 0, stream>>>(W_hh0, W_ih1, W_hh1, fc_out_w, W_ih0, fc_hidden_w,
                                    z, Wb_hh0, Wb_ih1, Wb_hh1, Wb_out, Wb_ih0z, Wb_fch, z_b);
  k_prep_emb<<<64, 256, 0, stream>>>(embed, W_ih0, egx);
  k_prep1<<<320, 256, 0, stream>>>(z_b, Wb_ih0z, Wb_fch, b_ih0, fc_hidden_b,
                                   zgx, h0f, h1f, h0b, h1b);

  GArgs a;
  a.zgx = zgx; a.egx = egx; a.target = target;
  a.h0f = h0f; a.h1f = h1f; a.h0b = h0b; a.h1b = h1b;
  a.p0 = p0; a.gx1a = gx1a; a.gx1b = gx1b; a.gh1 = gh1;
  a.Wb_hh0 = Wb_hh0; a.b_hh0 = b_hh0;
  a.Wb_ih1 = Wb_ih1; a.b_ih1 = b_ih1;
  a.Wb_hh1 = Wb_hh1; a.b_hh1 = b_hh1;
  a.Wb_out = Wb_out; a.fc_out_b = fc_out_b;
  a.out = out;

  // Skewed 2-launch pipeline, zero redundant work:
  //   A(t): G0(t)->p0 | X1(t-1)->gx1[(t-1)&1] | P1(t-2)+logits (reads gx1[t&1])
  //   C(t): Dp(t): pw0(p0)->h0 | G1(t-1)->gh1
  for (int t = 0; t <= T_ + 1; ++t) {
    k_A<<<896, 256, 49152, stream>>>(a, t);
    if (t <= T_) k_C<<<512, 256, 49152, stream>>>(a, t);
  }
}